// Round 4
// baseline (321.329 us; speedup 1.0000x reference)
//
#include <hip/hip_runtime.h>
#include <stdint.h>

// QuantumDeepField — MI355X (gfx950)
// Pipeline:
//   k_prep   : c_n, zz/qm split tables, layer-1 fold, W2/W3 -> bf16 linear,
//              out[b] = W_prop_b, zero M
//   k_corr   : systematic bf16-error correction at dens=0, adds G*corr to out
//   k_M      : M[b] = gto^T gto via MFMA, 1 barrier/block, replica atomics
//   k_red    : sum 8 replicas -> M
//   k_cct    : S_mo = e^T M e ; cct[b][d][a] bf16 linear
//   k_main   : BARRIER-FREE wave-local pipeline. Each wave owns 16 g-rows:
//              gto in-reg -> mo MFMA (B from L2) -> dens (shuffle) ->
//              v1 in-reg -> L2 MFMA -> v2 (wave-private LDS) -> L3 MFMA ->
//              esum -> atomic. 16.4 KB LDS, 256 thr, 4096 blocks.

#define BB 8
#define GG 32768
#define AA 64
#define DD 128
#define EPSF 1e-12f

// ---- workspace layout (byte offsets) ----
#define WS_M    0u          // [B][64][64] f32 Gram (131072 B)
#define WS_ZQ   131072u     // [B][ zz[64] | qm[64] ] f32 (4096 B)
#define WS_CN   135168u     // [B][64][128] f32 c_n (262144 B)
#define WS_UW   397312u     // u[128], w[128] f32 (1024 B)
#define WS_CCT  398336u     // [B][128 d][64 a] bf16 linear (131072 B)
#define WS_W2   529408u     // [128 e][128 d] bf16 linear (32768 B)
#define WS_W3   562176u     // [128 e][128 d] bf16 linear (32768 B)
#define WS_M8   594944u     // [8 rep][B][4096] f32 (1048576 B) -> end 1643520

typedef __attribute__((ext_vector_type(8))) short bf16x8;
typedef __attribute__((ext_vector_type(4))) float f32x4;

__device__ __forceinline__ unsigned short f2bf(float f) {
    union { float f; unsigned int u; } x; x.f = f;
    unsigned int u = x.u + 0x7FFFu + ((x.u >> 16) & 1u);
    return (unsigned short)(u >> 16);
}
__device__ __forceinline__ float bfround(float f) {
    union { float f; unsigned int u; } x; x.f = f;
    unsigned int u = x.u + 0x7FFFu + ((x.u >> 16) & 1u);
    x.u = u & 0xFFFF0000u;
    return x.f;
}
__device__ __forceinline__ float gto_eval(float dv, float zz, float qm) {
    float ttv = zz * dv;
    float ex = __expf(-ttv * ttv);
    float pw = (qm < 0.5f) ? 1.f : ((qm < 1.5f) ? dv : dv * dv);
    return pw * ex;
}

// ---------------- k_prep ----------------
__global__ __launch_bounds__(256)
void k_prep(const int* __restrict__ q, const int* __restrict__ ao,
            const float* __restrict__ coef, const float* __restrict__ zeta,
            const float* __restrict__ wpre_w, const float* __restrict__ wpre_b,
            const float* __restrict__ wfunc_w, const float* __restrict__ wfunc_b,
            const float* __restrict__ wprop_b, float* __restrict__ out,
            char* __restrict__ ws)
{
    int tid = blockIdx.x * 256 + threadIdx.x;
    if (tid < 32768) {
        // W2/W3 -> bf16 linear [e][d]
        int lsel = tid >> 14;
        int idx = tid & 16383;
        unsigned short* dst = (unsigned short*)(ws + (lsel == 0 ? WS_W2 : WS_W3));
        dst[idx] = f2bf(wfunc_w[(lsel + 1) * 16384 + idx]);
    } else if (tid < 33792) {
        // c_n: per-(b,d) L2 norm over A
        int i = tid - 32768;
        int b = i >> 7, dd = i & 127;
        float s = 0.f;
        for (int a = 0; a < AA; ++a) {
            float v = coef[ao[b * AA + a] * DD + dd];
            s += v * v;
        }
        float inv = 1.f / fmaxf(sqrtf(s), EPSF);
        float* cn = (float*)(ws + WS_CN);
        for (int a = 0; a < AA; ++a)
            cn[((size_t)b * AA + a) * DD + dd] = coef[ao[b * AA + a] * DD + dd] * inv;
    } else if (tid < 34304) {
        int i = tid - 33792;
        int b = i >> 6, a = i & 63;
        float* zq = (float*)(ws + WS_ZQ);
        zq[b * 128 + a]      = zeta[ao[b * AA + a]];
        zq[b * 128 + 64 + a] = (float)q[b * AA + a];   // q-1 in {0,1,2}
    } else if (tid < 34432) {
        // fold layer-1: u = W1 @ w_pre ; w = W1 @ b_pre + b1
        int e = tid - 34304;
        float su = 0.f, sw = 0.f;
        for (int dd = 0; dd < DD; ++dd) {
            float wv = wfunc_w[e * DD + dd];
            su += wv * wpre_w[dd];
            sw += wv * wpre_b[dd];
        }
        float* uw = (float*)(ws + WS_UW);
        uw[e] = su;
        uw[128 + e] = sw + wfunc_b[e];
    } else if (tid < 34440) {
        out[tid - 34432] = wprop_b[0];
    } else if (tid < 67208) {
        ((float*)(ws + WS_M))[tid - 34440] = 0.f;
    }
}

// ---------------- k_corr : cancel systematic bf16 error ----------------
__global__ __launch_bounds__(128)
void k_corr(const float* __restrict__ wfunc_w, const float* __restrict__ wfunc_b,
            const float* __restrict__ wprop_w, float* __restrict__ out,
            char* __restrict__ ws)
{
    __shared__ float v1e[128], v1b[128], v2e[128], v2b[128];
    __shared__ float part[2];
    int t = threadIdx.x;
    const float* uw = (const float*)(ws + WS_UW);
    float w0 = uw[128 + t];
    float r = fmaxf(w0, 0.f);
    v1e[t] = r;
    v1b[t] = bfround(r);
    __syncthreads();
    float ze = wfunc_b[128 + t], zb = ze;
    for (int dd = 0; dd < 128; ++dd) {
        float wv = wfunc_w[16384 + t * 128 + dd];
        ze += wv * v1e[dd];
        zb += bfround(wv) * v1b[dd];
    }
    v2e[t] = fmaxf(ze, 0.f);
    v2b[t] = bfround(fmaxf(zb, 0.f));
    __syncthreads();
    float ye = wfunc_b[256 + t], yb = ye;
    for (int dd = 0; dd < 128; ++dd) {
        float wv = wfunc_w[32768 + t * 128 + dd];
        ye += wv * v2e[dd];
        yb += bfround(wv) * v2b[dd];
    }
    float wpv = wprop_w[t];
    float diff = (fmaxf(ye, 0.f) - fmaxf(yb, 0.f)) * wpv;
    #pragma unroll
    for (int m = 1; m < 64; m <<= 1) diff += __shfl_xor(diff, m);
    if ((t & 63) == 0) part[t >> 6] = diff;
    __syncthreads();
    if (t == 0) {
        float corr = (part[0] + part[1]) * (float)GG;
        #pragma unroll
        for (int b = 0; b < BB; ++b) atomicAdd(&out[b], corr);
    }
}

// ---------------- k_M : Gram via MFMA, one barrier, replica atomics ----------
// grid (128, B), 256 thr. Block: 256 g = 2 tiles of 128, staged to 2 LDS bufs.
template<int NREP>
__global__ __launch_bounds__(256, 4)
void k_M(const float* __restrict__ dmat, char* __restrict__ ws)
{
    __shared__ unsigned short gs[2][8192];   // 2 x 16 KB, [64 a][128 g] swz
    const int b = blockIdx.y;
    const int chunk = blockIdx.x;            // 0..127
    const int t = threadIdx.x;
    const int g4 = t & 31, a8 = t >> 5;      // thread: 4 g x 8 a
    const int wv = t >> 6, l = t & 63;
    const int lrow = l & 15, lk = l >> 4;

    const float* zzp = (const float*)(ws + WS_ZQ) + b * 128;
    float4 za = *(const float4*)(zzp + a8 * 8);
    float4 zbv = *(const float4*)(zzp + a8 * 8 + 4);
    float4 qa = *(const float4*)(zzp + 64 + a8 * 8);
    float4 qb = *(const float4*)(zzp + 64 + a8 * 8 + 4);
    float zz8[8] = {za.x, za.y, za.z, za.w, zbv.x, zbv.y, zbv.z, zbv.w};
    float qm8[8] = {qa.x, qa.y, qa.z, qa.w, qb.x, qb.y, qb.z, qb.w};

    const float* dbase = dmat + ((size_t)b * GG + (size_t)chunk * 256) * AA;

    #pragma unroll
    for (int tt = 0; tt < 2; ++tt) {
        float gv[4][8];
        #pragma unroll
        for (int gg = 0; gg < 4; ++gg) {
            const float* rp = dbase + (size_t)(tt * 128 + g4 * 4 + gg) * AA + a8 * 8;
            float4 x0 = *(const float4*)rp;
            float4 x1 = *(const float4*)(rp + 4);
            float dv8[8] = {x0.x, x0.y, x0.z, x0.w, x1.x, x1.y, x1.z, x1.w};
            #pragma unroll
            for (int j = 0; j < 8; ++j) gv[gg][j] = gto_eval(dv8[j], zz8[j], qm8[j]);
        }
        #pragma unroll
        for (int j = 0; j < 8; ++j) {
            int a = a8 * 8 + j;
            unsigned int lo = (unsigned int)f2bf(gv[0][j]) | ((unsigned int)f2bf(gv[1][j]) << 16);
            unsigned int hi = (unsigned int)f2bf(gv[2][j]) | ((unsigned int)f2bf(gv[3][j]) << 16);
            *(uint2*)((char*)gs[tt] + a * 256 + ((g4 * 8) ^ ((a & 15) << 4))) = make_uint2(lo, hi);
        }
    }
    __syncthreads();

    f32x4 acc[4];
    #pragma unroll
    for (int rb = 0; rb < 4; ++rb) acc[rb] = (f32x4){0.f, 0.f, 0.f, 0.f};
    #pragma unroll
    for (int tt = 0; tt < 2; ++tt)
        #pragma unroll
        for (int kt = 0; kt < 4; ++kt) {
            int colB = kt * 64 + lk * 16;
            int ra = wv * 16 + lrow;
            bf16x8 af = *(const bf16x8*)((const char*)gs[tt] + ra * 256 + (colB ^ ((ra & 15) << 4)));
            #pragma unroll
            for (int rb = 0; rb < 4; ++rb) {
                int rr = rb * 16 + lrow;
                bf16x8 bv = *(const bf16x8*)((const char*)gs[tt] + rr * 256 + (colB ^ ((rr & 15) << 4)));
                acc[rb] = __builtin_amdgcn_mfma_f32_16x16x32_bf16(af, bv, acc[rb], 0, 0, 0);
            }
        }

    float* Mg = (float*)(ws + (NREP > 1 ? WS_M8 + (unsigned)(chunk & (NREP - 1)) * 131072u
                                        : WS_M)) + b * 4096;
    #pragma unroll
    for (int rb = 0; rb < 4; ++rb)
        #pragma unroll
        for (int r = 0; r < 4; ++r)
            atomicAdd(&Mg[(wv * 16 + lk * 4 + r) * 64 + rb * 16 + lrow], acc[rb][r]);
}

// ---------------- k_red : sum 8 replicas -> M ----------------
__global__ __launch_bounds__(256)
void k_red(char* __restrict__ ws)
{
    int i = blockIdx.x * 256 + threadIdx.x;     // 32768
    const float* rp = (const float*)(ws + WS_M8);
    float s = 0.f;
    #pragma unroll
    for (int r = 0; r < 8; ++r) s += rp[r * 32768 + i];
    ((float*)(ws + WS_M))[i] = s;
}

// ---------------- k_cct : S_mo = e^T M e ; folded coeffs (linear) ----------
__global__ __launch_bounds__(256)
void k_cct(const float* __restrict__ Ne, char* __restrict__ ws)
{
    __shared__ float M[64][64];
    __shared__ float e_s[128][65];
    __shared__ float inv_na[64];
    __shared__ float alpha[128];
    const int b = blockIdx.x, t = threadIdx.x;
    const float* Mg = (const float*)(ws + WS_M) + b * 4096;
    for (int i = t; i < 4096; i += 256) ((float*)M)[i] = Mg[i];
    __syncthreads();
    if (t < 64) inv_na[t] = 1.f / fmaxf(sqrtf(M[t][t]), EPSF);
    __syncthreads();
    const float* cn = (const float*)(ws + WS_CN) + (size_t)b * AA * DD;
    for (int i = t; i < 8192; i += 256) {
        int a = i >> 7, dd = i & 127;
        e_s[dd][a] = cn[a * DD + dd] * inv_na[a];
    }
    __syncthreads();
    const int d = t >> 1, half = t & 1;
    float y[32];
    #pragma unroll
    for (int j = 0; j < 32; ++j) y[j] = 0.f;
    for (int a = 0; a < 64; ++a) {
        float ea = e_s[d][a];
        const float4* Mr = (const float4*)&M[a][half * 32];
        #pragma unroll 8
        for (int j4 = 0; j4 < 8; ++j4) {
            float4 mv = Mr[j4];
            y[4 * j4 + 0] += ea * mv.x; y[4 * j4 + 1] += ea * mv.y;
            y[4 * j4 + 2] += ea * mv.z; y[4 * j4 + 3] += ea * mv.w;
        }
    }
    float s = 0.f;
    #pragma unroll 8
    for (int j = 0; j < 32; ++j) s += e_s[d][half * 32 + j] * y[j];
    s += __shfl_xor(s, 1);
    if (half == 0) alpha[d] = sqrtf(Ne[b] * (1.f / 128.f)) / fmaxf(sqrtf(s), EPSF);
    __syncthreads();
    unsigned short* cct = (unsigned short*)(ws + WS_CCT) + (size_t)b * 8192;
    for (int i = t; i < 8192; i += 256) {
        int dd = i >> 6, a = i & 63;
        cct[i] = f2bf(e_s[dd][a] * alpha[dd]);   // linear [d][a]
    }
}

// ---------------- k_main : barrier-free wave-local pipeline ----------------
// 4096 blocks x 256 thr. Wave wv owns rows g0 = tile*64 + wv*16 .. +16.
__global__ __launch_bounds__(256, 4)
void k_main(const float* __restrict__ dmat, const float* __restrict__ wfunc_b,
            const float* __restrict__ wprop_w, float* __restrict__ out,
            char* __restrict__ ws)
{
    __shared__ char v2buf[16384];    // 4 waves x [16 rows][256 B], swizzled
    __shared__ float bsum;

    const int t = threadIdx.x;
    const int b = blockIdx.x >> 9;
    const int tile = blockIdx.x & 511;
    const int wv = t >> 6, l = t & 63;
    const int lrow = l & 15, lk = l >> 4;

    if (t == 0) bsum = 0.f;

    const char* Wcct = (const char*)ws + WS_CCT + (size_t)b * 16384u;
    const char* W2g  = (const char*)ws + WS_W2;
    const char* W3g  = (const char*)ws + WS_W3;
    const float* zzp = (const float*)(ws + WS_ZQ) + b * 128;
    const float* uwp = (const float*)(ws + WS_UW);

    const float* drow = dmat + ((size_t)b * GG + (size_t)tile * 64 + wv * 16 + lrow) * AA;

    // ---- P2: mo GEMM (K=64), A(gto) built in registers ----
    f32x4 acc[8];
    #pragma unroll
    for (int j = 0; j < 8; ++j) acc[j] = (f32x4){0.f, 0.f, 0.f, 0.f};
    #pragma unroll
    for (int kt = 0; kt < 2; ++kt) {
        const int ab = kt * 32 + lk * 8;
        float4 d0 = *(const float4*)(drow + ab);
        float4 d1 = *(const float4*)(drow + ab + 4);
        float4 z0 = *(const float4*)(zzp + ab);
        float4 z1 = *(const float4*)(zzp + ab + 4);
        float4 q0 = *(const float4*)(zzp + 64 + ab);
        float4 q1 = *(const float4*)(zzp + 64 + ab + 4);
        float dv8[8] = {d0.x, d0.y, d0.z, d0.w, d1.x, d1.y, d1.z, d1.w};
        float zz8[8] = {z0.x, z0.y, z0.z, z0.w, z1.x, z1.y, z1.z, z1.w};
        float qm8[8] = {q0.x, q0.y, q0.z, q0.w, q1.x, q1.y, q1.z, q1.w};
        bf16x8 af;
        #pragma unroll
        for (int jj = 0; jj < 8; ++jj)
            af[jj] = (short)f2bf(gto_eval(dv8[jj], zz8[jj], qm8[jj]));
        #pragma unroll
        for (int j = 0; j < 8; ++j) {
            bf16x8 bv = *(const bf16x8*)(Wcct + (j * 16 + lrow) * 128 + kt * 64 + lk * 16);
            acc[j] = __builtin_amdgcn_mfma_f32_16x16x32_bf16(af, bv, acc[j], 0, 0, 0);
        }
    }

    // ---- density: wave-internal reduce (C cols are lanes 0..15 of each group)
    float p0 = 0.f, p1 = 0.f, p2 = 0.f, p3 = 0.f;
    #pragma unroll
    for (int j = 0; j < 8; ++j) {
        p0 += acc[j][0] * acc[j][0];
        p1 += acc[j][1] * acc[j][1];
        p2 += acc[j][2] * acc[j][2];
        p3 += acc[j][3] * acc[j][3];
    }
    #pragma unroll
    for (int m = 1; m < 16; m <<= 1) {
        p0 += __shfl_xor(p0, m); p1 += __shfl_xor(p1, m);
        p2 += __shfl_xor(p2, m); p3 += __shfl_xor(p3, m);
    }
    // lane group q=lk holds dens[rows q*4+r]; redistribute: lane wants row lrow
    {
        int src = (lrow >> 2) << 4;
        float e0 = __shfl(p0, src), e1 = __shfl(p1, src);
        float e2 = __shfl(p2, src), e3 = __shfl(p3, src);
        int rr = lrow & 3;
        p0 = (rr == 0) ? e0 : (rr == 1) ? e1 : (rr == 2) ? e2 : e3;   // dens[g row lrow]
    }
    const float dv = p0;

    // ---- P4: L2 GEMM, A(v1) built in registers from dens,u,w ----
    f32x4 acc2[8];
    #pragma unroll
    for (int j = 0; j < 8; ++j) acc2[j] = (f32x4){0.f, 0.f, 0.f, 0.f};
    #pragma unroll
    for (int kt = 0; kt < 4; ++kt) {
        const int db = kt * 32 + lk * 8;
        float4 u0 = *(const float4*)(uwp + db);
        float4 u1 = *(const float4*)(uwp + db + 4);
        float4 w0 = *(const float4*)(uwp + 128 + db);
        float4 w1 = *(const float4*)(uwp + 128 + db + 4);
        float uu[8] = {u0.x, u0.y, u0.z, u0.w, u1.x, u1.y, u1.z, u1.w};
        float ww[8] = {w0.x, w0.y, w0.z, w0.w, w1.x, w1.y, w1.z, w1.w};
        bf16x8 af;
        #pragma unroll
        for (int jj = 0; jj < 8; ++jj)
            af[jj] = (short)f2bf(fmaxf(dv * uu[jj] + ww[jj], 0.f));
        #pragma unroll
        for (int j = 0; j < 8; ++j) {
            bf16x8 bv = *(const bf16x8*)(W2g + (j * 16 + lrow) * 256 + kt * 64 + lk * 16);
            acc2[j] = __builtin_amdgcn_mfma_f32_16x16x32_bf16(af, bv, acc2[j], 0, 0, 0);
        }
    }

    // ---- v2 = relu(acc2+b2) -> wave-private LDS (no block barrier needed) ----
    char* vb = v2buf + wv * 4096;
    #pragma unroll
    for (int j = 0; j < 8; ++j) {
        float bias = wfunc_b[128 + j * 16 + lrow];
        #pragma unroll
        for (int r = 0; r < 4; ++r) {
            int row = lk * 4 + r;
            int colb = (j * 32 + lrow * 2) ^ ((row & 15) << 4);
            *(unsigned short*)(vb + row * 256 + colb) = f2bf(fmaxf(acc2[j][r] + bias, 0.f));
        }
    }

    // ---- P6: L3 GEMM, A(v2) from wave-private LDS ----
    f32x4 acc3[8];
    #pragma unroll
    for (int j = 0; j < 8; ++j) acc3[j] = (f32x4){0.f, 0.f, 0.f, 0.f};
    #pragma unroll
    for (int kt = 0; kt < 4; ++kt) {
        bf16x8 af = *(const bf16x8*)(vb + lrow * 256 +
                                     ((kt * 64 + lk * 16) ^ ((lrow & 15) << 4)));
        #pragma unroll
        for (int j = 0; j < 8; ++j) {
            bf16x8 bv = *(const bf16x8*)(W3g + (j * 16 + lrow) * 256 + kt * 64 + lk * 16);
            acc3[j] = __builtin_amdgcn_mfma_f32_16x16x32_bf16(af, bv, acc3[j], 0, 0, 0);
        }
    }

    // ---- epilogue: esum = sum relu(acc3+b3)*wprop ----
    float esum = 0.f;
    #pragma unroll
    for (int j = 0; j < 8; ++j) {
        float bias = wfunc_b[256 + j * 16 + lrow];
        float wpv = wprop_w[j * 16 + lrow];
        #pragma unroll
        for (int r = 0; r < 4; ++r)
            esum += fmaxf(acc3[j][r] + bias, 0.f) * wpv;
    }
    #pragma unroll
    for (int m = 1; m < 64; m <<= 1) esum += __shfl_xor(esum, m);
    __syncthreads();                      // bsum=0 visible; all waves done
    if (l == 0) atomicAdd(&bsum, esum);
    __syncthreads();
    if (t == 0) atomicAdd(&out[b], bsum);
}

// ---------------- launcher ----------------
extern "C" void kernel_launch(void* const* d_in, const int* in_sizes, int n_in,
                              void* d_out, int out_size, void* d_ws, size_t ws_size,
                              hipStream_t stream)
{
    const float* dmat    = (const float*)d_in[0];
    const int*   q       = (const int*)d_in[1];
    const int*   ao      = (const int*)d_in[2];
    const float* Ne      = (const float*)d_in[3];
    const float* coef    = (const float*)d_in[4];
    const float* zeta    = (const float*)d_in[5];
    const float* wpre_w  = (const float*)d_in[6];
    const float* wpre_b  = (const float*)d_in[7];
    const float* wfunc_w = (const float*)d_in[8];
    const float* wfunc_b = (const float*)d_in[9];
    const float* wprop_w = (const float*)d_in[10];
    const float* wprop_b = (const float*)d_in[11];
    float* out = (float*)d_out;
    char*  ws  = (char*)d_ws;

    const bool rep = ws_size >= (size_t)(WS_M8 + 1048576u);

    k_prep<<<263, 256, 0, stream>>>(q, ao, coef, zeta, wpre_w, wpre_b,
                                    wfunc_w, wfunc_b, wprop_b, out, ws);
    k_corr<<<1, 128, 0, stream>>>(wfunc_w, wfunc_b, wprop_w, out, ws);
    if (rep) {
        hipMemsetAsync(ws + WS_M8, 0, 1048576, stream);
        k_M<8><<<dim3(128, BB), 256, 0, stream>>>(dmat, ws);
        k_red<<<128, 256, 0, stream>>>(ws);
    } else {
        k_M<1><<<dim3(128, BB), 256, 0, stream>>>(dmat, ws);
    }
    k_cct<<<BB, 256, 0, stream>>>(Ne, ws);
    k_main<<<4096, 256, 0, stream>>>(dmat, wfunc_b, wprop_w, out, ws);
}

// Round 5
// 226.935 us; speedup vs baseline: 1.4160x; 1.4160x over previous
//
#include <hip/hip_runtime.h>
#include <stdint.h>

// QuantumDeepField — MI355X (gfx950)
// Decomposed pipeline (dens[b,g] is the 1MB narrow point):
//   k_prep  : W2/W3->bf16 linear, c_n, zz/qm, out[b]=bias, zero M
//   k_corr2 : coalesced layer-1 fold (u,w) + systematic bf16-error correction
//   k_gto   : dmat -> gto bf16 (ws, [b][g][a]) + Gram M via MFMA (replicas)
//   k_red   : sum replicas -> M
//   k_cct   : S_mo = e^T M e ; cct[b][d][a] bf16 linear
//   k_dens  : gto x cct(LDS swz) -> dens[b][g] f32
//   k_mlp   : dens -> v1(reg) -> L2 GEMM (W2 LDS swz) -> v2(wave LDS) ->
//             L3 GEMM (W3 LDS swz) -> esum -> out[b]

#define BB 8
#define GG 32768
#define AA 64
#define DD 128
#define EPSF 1e-12f

// ---- workspace layout (byte offsets) ----
#define WS_M    0u          // [B][64][64] f32 Gram (131072)
#define WS_ZQ   131072u     // [B][ zz[64] | qm[64] ] f32 (4096)
#define WS_CN   135168u     // [B][64][128] f32 c_n (262144)
#define WS_UW   397312u     // u[128], w[128] f32 (1024)
#define WS_CCT  398336u     // [B][128 d][64 a] bf16 linear (131072)
#define WS_W2   529408u     // [128 e][128 d] bf16 linear (32768)
#define WS_W3   562176u     // [128 e][128 d] bf16 linear (32768)
#define WS_DENS 594944u     // [B][32768] f32 (1048576) -> 1643520
#define WS_M8   1643520u    // [8 rep][B][4096] f32 (1048576) -> 2692096
#define WS_GTO  2692096u    // [B][32768][64] bf16 (33554432) -> 36246528
#define WS_END  36246528u

typedef __attribute__((ext_vector_type(8))) short bf16x8;
typedef __attribute__((ext_vector_type(4))) float f32x4;

__device__ __forceinline__ unsigned short f2bf(float f) {
    union { float f; unsigned int u; } x; x.f = f;
    unsigned int u = x.u + 0x7FFFu + ((x.u >> 16) & 1u);
    return (unsigned short)(u >> 16);
}
__device__ __forceinline__ float bfround(float f) {
    union { float f; unsigned int u; } x; x.f = f;
    unsigned int u = x.u + 0x7FFFu + ((x.u >> 16) & 1u);
    x.u = u & 0xFFFF0000u;
    return x.f;
}
__device__ __forceinline__ float gto_eval(float dv, float zz, float qm) {
    float ttv = zz * dv;
    float ex = __expf(-ttv * ttv);
    float pw = (qm < 0.5f) ? 1.f : ((qm < 1.5f) ? dv : dv * dv);
    return pw * ex;
}

// ---------------- k_prep ----------------
__global__ __launch_bounds__(256)
void k_prep(const int* __restrict__ q, const int* __restrict__ ao,
            const float* __restrict__ coef, const float* __restrict__ zeta,
            const float* __restrict__ wfunc_w, const float* __restrict__ wprop_b,
            float* __restrict__ out, char* __restrict__ ws)
{
    int tid = blockIdx.x * 256 + threadIdx.x;
    if (tid < 32768) {
        int lsel = tid >> 14;           // 0 -> layer 2, 1 -> layer 3
        int idx = tid & 16383;
        unsigned short* dst = (unsigned short*)(ws + (lsel == 0 ? WS_W2 : WS_W3));
        dst[idx] = f2bf(wfunc_w[(lsel + 1) * 16384 + idx]);
    } else if (tid < 33792) {
        // c_n: per-(b,d) L2 norm over A
        int i = tid - 32768;
        int b = i >> 7, dd = i & 127;
        float s = 0.f;
        for (int a = 0; a < AA; ++a) {
            float v = coef[ao[b * AA + a] * DD + dd];
            s += v * v;
        }
        float inv = 1.f / fmaxf(sqrtf(s), EPSF);
        float* cn = (float*)(ws + WS_CN);
        for (int a = 0; a < AA; ++a)
            cn[((size_t)b * AA + a) * DD + dd] = coef[ao[b * AA + a] * DD + dd] * inv;
    } else if (tid < 34304) {
        int i = tid - 33792;
        int b = i >> 6, a = i & 63;
        float* zq = (float*)(ws + WS_ZQ);
        zq[b * 128 + a]      = zeta[ao[b * AA + a]];
        zq[b * 128 + 64 + a] = (float)q[b * AA + a];
    } else if (tid < 34312) {
        out[tid - 34304] = wprop_b[0];
    } else if (tid < 67080) {
        ((float*)(ws + WS_M))[tid - 34312] = 0.f;
    }
}

// ---------------- k_corr2 : uw fold + bf16 correction (coalesced) ----------
__global__ __launch_bounds__(1024)
void k_corr2(const float* __restrict__ wpre_w, const float* __restrict__ wpre_b,
             const float* __restrict__ wfunc_w, const float* __restrict__ wfunc_b,
             const float* __restrict__ wprop_w, float* __restrict__ out,
             char* __restrict__ ws)
{
    __shared__ float v1e[128], v1b[128], v2e[128], v2b[128];
    __shared__ float red;
    const int t = threadIdx.x, e = t >> 3, s = t & 7;
    if (t == 0) red = 0.f;
    float* uw = (float*)(ws + WS_UW);

    // phase A: u[e] = W1[e].wpre_w ; w[e] = W1[e].wpre_b + b1[e]
    float su = 0.f, sw = 0.f;
    {
        const float* W1r = wfunc_w + e * 128 + s * 16;
        const float* pw  = wpre_w + s * 16;
        const float* pb  = wpre_b + s * 16;
        #pragma unroll
        for (int k = 0; k < 4; ++k) {
            float4 wv = *(const float4*)(W1r + k * 4);
            float4 a  = *(const float4*)(pw + k * 4);
            float4 bq = *(const float4*)(pb + k * 4);
            su += wv.x * a.x + wv.y * a.y + wv.z * a.z + wv.w * a.w;
            sw += wv.x * bq.x + wv.y * bq.y + wv.z * bq.z + wv.w * bq.w;
        }
    }
    #pragma unroll
    for (int m = 1; m < 8; m <<= 1) { su += __shfl_xor(su, m); sw += __shfl_xor(sw, m); }
    if (s == 0) {
        float w0 = sw + wfunc_b[e];
        uw[e] = su; uw[128 + e] = w0;
        float r = fmaxf(w0, 0.f);
        v1e[e] = r; v1b[e] = bfround(r);
    }
    __syncthreads();

    // phase B: layer 2 at dens=0 (exact vs bf16 paths)
    float ze = 0.f, zb = 0.f;
    {
        const float* W2r = wfunc_w + 16384 + e * 128 + s * 16;
        #pragma unroll
        for (int k = 0; k < 16; ++k) {
            float wv = W2r[k];
            ze += wv * v1e[s * 16 + k];
            zb += bfround(wv) * v1b[s * 16 + k];
        }
    }
    #pragma unroll
    for (int m = 1; m < 8; m <<= 1) { ze += __shfl_xor(ze, m); zb += __shfl_xor(zb, m); }
    if (s == 0) {
        float bias = wfunc_b[128 + e];
        v2e[e] = fmaxf(ze + bias, 0.f);
        v2b[e] = bfround(fmaxf(zb + bias, 0.f));
    }
    __syncthreads();

    // phase C: layer 3 + wprop, diff
    float ye = 0.f, yb = 0.f;
    {
        const float* W3r = wfunc_w + 32768 + e * 128 + s * 16;
        #pragma unroll
        for (int k = 0; k < 16; ++k) {
            float wv = W3r[k];
            ye += wv * v2e[s * 16 + k];
            yb += bfround(wv) * v2b[s * 16 + k];
        }
    }
    #pragma unroll
    for (int m = 1; m < 8; m <<= 1) { ye += __shfl_xor(ye, m); yb += __shfl_xor(yb, m); }
    if (s == 0) {
        float bias = wfunc_b[256 + e];
        float diff = (fmaxf(ye + bias, 0.f) - fmaxf(yb + bias, 0.f)) * wprop_w[e];
        atomicAdd(&red, diff);
    }
    __syncthreads();
    if (t == 0) {
        float corr = red * (float)GG;
        #pragma unroll
        for (int b = 0; b < BB; ++b) atomicAdd(&out[b], corr);
    }
}

// ---------------- k_gto : gto bf16 store + Gram via MFMA ----------------
// grid (128, B), 256 thr; per block 256 g = 2 tiles of 128.
template<int NREP, bool STORE>
__global__ __launch_bounds__(256, 4)
void k_gto(const float* __restrict__ dmat, char* __restrict__ ws)
{
    __shared__ unsigned short gs[2][8192];   // [64 a][128 g] swz
    const int b = blockIdx.y;
    const int chunk = blockIdx.x;            // 0..127
    const int t = threadIdx.x;
    const int g4 = t & 31, a8 = t >> 5;      // 4 g x 8 a per thread
    const int wv = t >> 6, l = t & 63;
    const int lrow = l & 15, lk = l >> 4;

    const float* zzp = (const float*)(ws + WS_ZQ) + b * 128;
    float4 za = *(const float4*)(zzp + a8 * 8);
    float4 zbv = *(const float4*)(zzp + a8 * 8 + 4);
    float4 qa = *(const float4*)(zzp + 64 + a8 * 8);
    float4 qb = *(const float4*)(zzp + 64 + a8 * 8 + 4);
    float zz8[8] = {za.x, za.y, za.z, za.w, zbv.x, zbv.y, zbv.z, zbv.w};
    float qm8[8] = {qa.x, qa.y, qa.z, qa.w, qb.x, qb.y, qb.z, qb.w};

    const float* dbase = dmat + ((size_t)b * GG + (size_t)chunk * 256) * AA;
    unsigned short* gto = (unsigned short*)(ws + WS_GTO);

    #pragma unroll
    for (int tt = 0; tt < 2; ++tt) {
        float gv[4][8];
        #pragma unroll
        for (int gg = 0; gg < 4; ++gg) {
            const float* rp = dbase + (size_t)(tt * 128 + g4 * 4 + gg) * AA + a8 * 8;
            float4 x0 = *(const float4*)rp;
            float4 x1 = *(const float4*)(rp + 4);
            float dv8[8] = {x0.x, x0.y, x0.z, x0.w, x1.x, x1.y, x1.z, x1.w};
            #pragma unroll
            for (int j = 0; j < 8; ++j) gv[gg][j] = gto_eval(dv8[j], zz8[j], qm8[j]);
        }
        #pragma unroll
        for (int j = 0; j < 8; ++j) {
            int a = a8 * 8 + j;
            unsigned int lo = (unsigned int)f2bf(gv[0][j]) | ((unsigned int)f2bf(gv[1][j]) << 16);
            unsigned int hi = (unsigned int)f2bf(gv[2][j]) | ((unsigned int)f2bf(gv[3][j]) << 16);
            *(uint2*)((char*)gs[tt] + a * 256 + ((g4 * 8) ^ ((a & 15) << 4))) = make_uint2(lo, hi);
        }
        if (STORE) {
            #pragma unroll
            for (int gg = 0; gg < 4; ++gg) {
                unsigned int w0 = (unsigned int)f2bf(gv[gg][0]) | ((unsigned int)f2bf(gv[gg][1]) << 16);
                unsigned int w1 = (unsigned int)f2bf(gv[gg][2]) | ((unsigned int)f2bf(gv[gg][3]) << 16);
                unsigned int w2 = (unsigned int)f2bf(gv[gg][4]) | ((unsigned int)f2bf(gv[gg][5]) << 16);
                unsigned int w3 = (unsigned int)f2bf(gv[gg][6]) | ((unsigned int)f2bf(gv[gg][7]) << 16);
                size_t go = ((size_t)b * GG + (size_t)chunk * 256 + tt * 128 + g4 * 4 + gg) * AA + a8 * 8;
                *(uint4*)(gto + go) = make_uint4(w0, w1, w2, w3);
            }
        }
    }
    __syncthreads();

    f32x4 acc[4];
    #pragma unroll
    for (int rb = 0; rb < 4; ++rb) acc[rb] = (f32x4){0.f, 0.f, 0.f, 0.f};
    #pragma unroll
    for (int tt = 0; tt < 2; ++tt)
        #pragma unroll
        for (int kt = 0; kt < 4; ++kt) {
            int colB = kt * 64 + lk * 16;
            int ra = wv * 16 + lrow;
            bf16x8 af = *(const bf16x8*)((const char*)gs[tt] + ra * 256 + (colB ^ ((ra & 15) << 4)));
            #pragma unroll
            for (int rb = 0; rb < 4; ++rb) {
                int rr = rb * 16 + lrow;
                bf16x8 bv = *(const bf16x8*)((const char*)gs[tt] + rr * 256 + (colB ^ ((rr & 15) << 4)));
                acc[rb] = __builtin_amdgcn_mfma_f32_16x16x32_bf16(af, bv, acc[rb], 0, 0, 0);
            }
        }

    float* Mg = (float*)(ws + (NREP > 1 ? WS_M8 + (unsigned)(chunk & (NREP - 1)) * 131072u
                                        : WS_M)) + b * 4096;
    #pragma unroll
    for (int rb = 0; rb < 4; ++rb)
        #pragma unroll
        for (int r = 0; r < 4; ++r)
            atomicAdd(&Mg[(wv * 16 + lk * 4 + r) * 64 + rb * 16 + lrow], acc[rb][r]);
}

// ---------------- k_red ----------------
__global__ __launch_bounds__(256)
void k_red(char* __restrict__ ws)
{
    int i = blockIdx.x * 256 + threadIdx.x;     // 32768
    const float* rp = (const float*)(ws + WS_M8);
    float s = 0.f;
    #pragma unroll
    for (int r = 0; r < 8; ++r) s += rp[r * 32768 + i];
    ((float*)(ws + WS_M))[i] = s;
}

// ---------------- k_cct ----------------
__global__ __launch_bounds__(256)
void k_cct(const float* __restrict__ Ne, char* __restrict__ ws)
{
    __shared__ float M[64][64];
    __shared__ float e_s[128][65];
    __shared__ float inv_na[64];
    __shared__ float alpha[128];
    const int b = blockIdx.x, t = threadIdx.x;
    const float* Mg = (const float*)(ws + WS_M) + b * 4096;
    for (int i = t; i < 4096; i += 256) ((float*)M)[i] = Mg[i];
    __syncthreads();
    if (t < 64) inv_na[t] = 1.f / fmaxf(sqrtf(M[t][t]), EPSF);
    __syncthreads();
    const float* cn = (const float*)(ws + WS_CN) + (size_t)b * AA * DD;
    for (int i = t; i < 8192; i += 256) {
        int a = i >> 7, dd = i & 127;
        e_s[dd][a] = cn[a * DD + dd] * inv_na[a];
    }
    __syncthreads();
    const int d = t >> 1, half = t & 1;
    float y[32];
    #pragma unroll
    for (int j = 0; j < 32; ++j) y[j] = 0.f;
    for (int a = 0; a < 64; ++a) {
        float ea = e_s[d][a];
        const float4* Mr = (const float4*)&M[a][half * 32];
        #pragma unroll 8
        for (int j4 = 0; j4 < 8; ++j4) {
            float4 mv = Mr[j4];
            y[4 * j4 + 0] += ea * mv.x; y[4 * j4 + 1] += ea * mv.y;
            y[4 * j4 + 2] += ea * mv.z; y[4 * j4 + 3] += ea * mv.w;
        }
    }
    float s = 0.f;
    #pragma unroll 8
    for (int j = 0; j < 32; ++j) s += e_s[d][half * 32 + j] * y[j];
    s += __shfl_xor(s, 1);
    if (half == 0) alpha[d] = sqrtf(Ne[b] * (1.f / 128.f)) / fmaxf(sqrtf(s), EPSF);
    __syncthreads();
    unsigned short* cct = (unsigned short*)(ws + WS_CCT) + (size_t)b * 8192;
    for (int i = t; i < 8192; i += 256) {
        int dd = i >> 6, a = i & 63;
        cct[i] = f2bf(e_s[dd][a] * alpha[dd]);   // linear [d][a]
    }
}

// ---------------- k_dens : mo GEMM -> dens[b][g] ----------------
// grid 1024 (b = bid>>7), 256 thr; per wave 4 tiles of 16 rows.
template<bool STORE>
__global__ __launch_bounds__(256, 2)
void k_dens(const float* __restrict__ dmat, char* __restrict__ ws)
{
    __shared__ unsigned short ccts[8192];    // [128 d][64 a] swz
    const int t = threadIdx.x;
    const int b = blockIdx.x >> 7;
    const int blk = blockIdx.x & 127;
    const int wv = t >> 6, l = t & 63;
    const int lrow = l & 15, lk = l >> 4;

    {   // stage cct swizzled
        const uint4* src = (const uint4*)(ws + WS_CCT + (size_t)b * 16384u);
        for (int i = t; i < 1024; i += 256) {
            int off = i * 16;
            int dd = (off >> 7) & 7;
            *(uint4*)((char*)ccts + (off ^ (dd << 4))) = src[i];
        }
    }
    __syncthreads();

    const unsigned short* gto = (const unsigned short*)(ws + WS_GTO);
    float* densp = (float*)(ws + WS_DENS) + (size_t)b * GG;
    const float* zzp = (const float*)(ws + WS_ZQ) + b * 128;

    for (int it = 0; it < 4; ++it) {
        const int g0 = blk * 256 + it * 64 + wv * 16;
        const int g = g0 + lrow;
        f32x4 acc[8];
        #pragma unroll
        for (int j = 0; j < 8; ++j) acc[j] = (f32x4){0.f, 0.f, 0.f, 0.f};
        #pragma unroll
        for (int kt = 0; kt < 2; ++kt) {
            bf16x8 af;
            if (STORE) {
                af = *(const bf16x8*)(gto + ((size_t)b * GG + g) * AA + kt * 32 + lk * 8);
            } else {
                const int a0 = kt * 32 + lk * 8;
                const float* rp = dmat + ((size_t)b * GG + g) * AA + a0;
                float4 x0 = *(const float4*)rp;
                float4 x1 = *(const float4*)(rp + 4);
                float4 z0 = *(const float4*)(zzp + a0);
                float4 z1 = *(const float4*)(zzp + a0 + 4);
                float4 q0 = *(const float4*)(zzp + 64 + a0);
                float4 q1 = *(const float4*)(zzp + 64 + a0 + 4);
                float dv8[8] = {x0.x, x0.y, x0.z, x0.w, x1.x, x1.y, x1.z, x1.w};
                float zz8[8] = {z0.x, z0.y, z0.z, z0.w, z1.x, z1.y, z1.z, z1.w};
                float qm8[8] = {q0.x, q0.y, q0.z, q0.w, q1.x, q1.y, q1.z, q1.w};
                #pragma unroll
                for (int jj = 0; jj < 8; ++jj)
                    af[jj] = (short)f2bf(gto_eval(dv8[jj], zz8[jj], qm8[jj]));
            }
            #pragma unroll
            for (int j = 0; j < 8; ++j) {
                int dr = j * 16 + lrow;
                bf16x8 bv = *(const bf16x8*)((const char*)ccts + dr * 128 +
                                             ((kt * 64 + lk * 16) ^ ((dr & 7) << 4)));
                acc[j] = __builtin_amdgcn_mfma_f32_16x16x32_bf16(af, bv, acc[j], 0, 0, 0);
            }
        }
        float p0 = 0.f, p1 = 0.f, p2 = 0.f, p3 = 0.f;
        #pragma unroll
        for (int j = 0; j < 8; ++j) {
            p0 += acc[j][0] * acc[j][0];
            p1 += acc[j][1] * acc[j][1];
            p2 += acc[j][2] * acc[j][2];
            p3 += acc[j][3] * acc[j][3];
        }
        #pragma unroll
        for (int m = 1; m < 16; m <<= 1) {
            p0 += __shfl_xor(p0, m); p1 += __shfl_xor(p1, m);
            p2 += __shfl_xor(p2, m); p3 += __shfl_xor(p3, m);
        }
        int src = (lrow >> 2) << 4;
        float e0 = __shfl(p0, src), e1 = __shfl(p1, src);
        float e2 = __shfl(p2, src), e3 = __shfl(p3, src);
        int rr = lrow & 3;
        float dv = (rr == 0) ? e0 : (rr == 1) ? e1 : (rr == 2) ? e2 : e3;
        if (lk == 0) densp[g0 + lrow] = dv;
    }
}

// ---------------- k_mlp : dens -> E contribution ----------------
// grid 512 (b = bid>>6), 256 thr, dynamic LDS 80KB (2 blocks/CU).
#define SMEM_MLP 81920
__global__ __launch_bounds__(256, 2)
void k_mlp(const float* __restrict__ wfunc_b, const float* __restrict__ wprop_w,
           float* __restrict__ out, char* __restrict__ ws)
{
    extern __shared__ char lds[];   // 0..32K W2 swz, 32K..64K W3 swz, 64K.. v2buf
    const int t = threadIdx.x;
    const int b = blockIdx.x >> 6;
    const int blk = blockIdx.x & 63;
    const int wv = t >> 6, l = t & 63;
    const int lrow = l & 15, lk = l >> 4;

    {   // stage W2|W3 (contiguous 64KB in ws) swizzled
        const uint4* src = (const uint4*)(ws + WS_W2);
        for (int i = t; i < 4096; i += 256) {
            int off = i * 16;
            int e = (off >> 8) & 7;
            *(uint4*)(lds + (off ^ (e << 4))) = src[i];
        }
    }
    float b2r[8], b3r[8], wpr[8];
    #pragma unroll
    for (int j = 0; j < 8; ++j) {
        b2r[j] = wfunc_b[128 + j * 16 + lrow];
        b3r[j] = wfunc_b[256 + j * 16 + lrow];
        wpr[j] = wprop_w[j * 16 + lrow];
    }
    const float* uwp = (const float*)(ws + WS_UW);
    const float* densp = (const float*)(ws + WS_DENS) + (size_t)b * GG;
    char* vb = lds + 65536 + wv * 4096;
    __syncthreads();

    float esum = 0.f;
    for (int it = 0; it < 4; ++it) {
        const int g0 = blk * 512 + wv * 128 + it * 32;
        float dv0 = densp[g0 + lrow];
        float dv1 = densp[g0 + 16 + lrow];
        f32x4 acc2[2][8];
        #pragma unroll
        for (int i = 0; i < 2; ++i)
            #pragma unroll
            for (int j = 0; j < 8; ++j) acc2[i][j] = (f32x4){0.f, 0.f, 0.f, 0.f};
        #pragma unroll
        for (int kt = 0; kt < 4; ++kt) {
            const int d0 = kt * 32 + lk * 8;
            float4 u0 = *(const float4*)(uwp + d0);
            float4 u1 = *(const float4*)(uwp + d0 + 4);
            float4 w0 = *(const float4*)(uwp + 128 + d0);
            float4 w1 = *(const float4*)(uwp + 128 + d0 + 4);
            float uu[8] = {u0.x, u0.y, u0.z, u0.w, u1.x, u1.y, u1.z, u1.w};
            float ww[8] = {w0.x, w0.y, w0.z, w0.w, w1.x, w1.y, w1.z, w1.w};
            bf16x8 af0, af1;
            #pragma unroll
            for (int jj = 0; jj < 8; ++jj) {
                af0[jj] = (short)f2bf(fmaxf(dv0 * uu[jj] + ww[jj], 0.f));
                af1[jj] = (short)f2bf(fmaxf(dv1 * uu[jj] + ww[jj], 0.f));
            }
            #pragma unroll
            for (int j = 0; j < 8; ++j) {
                int e = j * 16 + lrow;
                bf16x8 bv = *(const bf16x8*)(lds + e * 256 +
                                             ((kt * 64 + lk * 16) ^ ((e & 7) << 4)));
                acc2[0][j] = __builtin_amdgcn_mfma_f32_16x16x32_bf16(af0, bv, acc2[0][j], 0, 0, 0);
                acc2[1][j] = __builtin_amdgcn_mfma_f32_16x16x32_bf16(af1, bv, acc2[1][j], 0, 0, 0);
            }
        }
        #pragma unroll
        for (int h = 0; h < 2; ++h) {
            // v2 half -> wave-private LDS (16 rows x 256B, swz)
            #pragma unroll
            for (int j = 0; j < 8; ++j) {
                int e = j * 16 + lrow;
                #pragma unroll
                for (int r = 0; r < 4; ++r) {
                    int row = lk * 4 + r;
                    *(unsigned short*)(vb + row * 256 + ((e * 2) ^ ((row & 7) << 4))) =
                        f2bf(fmaxf(acc2[h][j][r] + b2r[j], 0.f));
                }
            }
            f32x4 acc3[8];
            #pragma unroll
            for (int j = 0; j < 8; ++j) acc3[j] = (f32x4){0.f, 0.f, 0.f, 0.f};
            #pragma unroll
            for (int kt = 0; kt < 4; ++kt) {
                bf16x8 af = *(const bf16x8*)(vb + lrow * 256 +
                                             ((kt * 64 + lk * 16) ^ ((lrow & 7) << 4)));
                #pragma unroll
                for (int j = 0; j < 8; ++j) {
                    int e = j * 16 + lrow;
                    bf16x8 bv = *(const bf16x8*)(lds + 32768 + e * 256 +
                                                 ((kt * 64 + lk * 16) ^ ((e & 7) << 4)));
                    acc3[j] = __builtin_amdgcn_mfma_f32_16x16x32_bf16(af, bv, acc3[j], 0, 0, 0);
                }
            }
            #pragma unroll
            for (int j = 0; j < 8; ++j)
                #pragma unroll
                for (int r = 0; r < 4; ++r)
                    esum += fmaxf(acc3[j][r] + b3r[j], 0.f) * wpr[j];
        }
    }
    #pragma unroll
    for (int m = 1; m < 64; m <<= 1) esum += __shfl_xor(esum, m);
    if (l == 0) atomicAdd(&out[b], esum);
}

// ---------------- launcher ----------------
extern "C" void kernel_launch(void* const* d_in, const int* in_sizes, int n_in,
                              void* d_out, int out_size, void* d_ws, size_t ws_size,
                              hipStream_t stream)
{
    const float* dmat    = (const float*)d_in[0];
    const int*   q       = (const int*)d_in[1];
    const int*   ao      = (const int*)d_in[2];
    const float* Ne      = (const float*)d_in[3];
    const float* coef    = (const float*)d_in[4];
    const float* zeta    = (const float*)d_in[5];
    const float* wpre_w  = (const float*)d_in[6];
    const float* wpre_b  = (const float*)d_in[7];
    const float* wfunc_w = (const float*)d_in[8];
    const float* wfunc_b = (const float*)d_in[9];
    const float* wprop_w = (const float*)d_in[10];
    const float* wprop_b = (const float*)d_in[11];
    float* out = (float*)d_out;
    char*  ws  = (char*)d_ws;

    const bool rep = ws_size >= (size_t)(WS_M8 + 1048576u);
    const bool sg  = ws_size >= (size_t)WS_END;

    k_prep<<<263, 256, 0, stream>>>(q, ao, coef, zeta, wfunc_w, wprop_b, out, ws);
    k_corr2<<<1, 1024, 0, stream>>>(wpre_w, wpre_b, wfunc_w, wfunc_b, wprop_w, out, ws);
    if (rep) {
        hipMemsetAsync(ws + WS_M8, 0, 1048576, stream);
        if (sg) k_gto<8, true><<<dim3(128, BB), 256, 0, stream>>>(dmat, ws);
        else    k_gto<8, false><<<dim3(128, BB), 256, 0, stream>>>(dmat, ws);
        k_red<<<128, 256, 0, stream>>>(ws);
    } else {
        k_gto<1, false><<<dim3(128, BB), 256, 0, stream>>>(dmat, ws);
    }
    k_cct<<<BB, 256, 0, stream>>>(Ne, ws);
    if (sg) k_dens<true><<<1024, 256, 0, stream>>>(dmat, ws);
    else    k_dens<false><<<1024, 256, 0, stream>>>(dmat, ws);
    hipFuncSetAttribute((const void*)k_mlp,
                        hipFuncAttributeMaxDynamicSharedMemorySize, SMEM_MLP);
    k_mlp<<<512, 256, SMEM_MLP, stream>>>(wfunc_b, wprop_w, out, ws);
}